// Round 1
// baseline (604.380 us; speedup 1.0000x reference)
//
#include <hip/hip_runtime.h>

// EMA recurrence over s for x[4, 4096, 2048] fp32 — single fused kernel.
// Decoupled chunk scan: each block (xb, j) computes its chunk's zero-init
// EMA final, publishes it (BEFORE any waiting -> no deadlock), barrier-AND
// waits for all predecessor chunk flags, Horners the carry (identical
// numerics to the previous two-pass K2), then rescans its chunk (L2/L3-hot)
// and nontemporal-stores out. A tiny pre-kernel zeroes the flags each
// replay (ws is re-poisoned by the harness between iterations).

namespace {

constexpr int B  = 4;
constexpr int S  = 4096;
constexpr int D  = 2048;
constexpr int D4 = D / 4;          // 512 float4 per (b,s) row
constexpr int NCOL4 = B * D4;      // 2048 float4-columns
constexpr int BLOCK = 256;
constexpr int XB = NCOL4 / BLOCK;  // 8 column-blocks

// Native vector type for nontemporal builtins.
typedef float v4f __attribute__((ext_vector_type(4)));

// Match the reference's fp32 constants exactly.
constexpr float kA  = 0.99f;
constexpr float kOm = (float)(1.0 - 0.99);      // 0.009999999776482582f

// 0.99^L in double (L power of two), rounded to float once.
constexpr double alpha_pow_pow2(int l) {
    double t = 0.99;
    while (l > 1) { t *= t; l >>= 1; }
    return t;
}

__global__ __launch_bounds__(256)
void zero_flags(int* __restrict__ flags, int n) {
    int i = blockIdx.x * 256 + threadIdx.x;
    if (i < n) flags[i] = 0;
}

template <int NCHUNK>
__global__ __launch_bounds__(BLOCK, 4)   // cap VGPR<=128 -> 4 blocks/CU, full grid co-resident
void cema_fused(const float4* __restrict__ x, float4* __restrict__ out,
                float4* __restrict__ part, int* __restrict__ flags) {
    constexpr int L = S / NCHUNK;
    constexpr float aL = (float)alpha_pow_pow2(L);

    const int xb = blockIdx.x;
    const int c  = xb * BLOCK + threadIdx.x;   // col4 index
    const int j  = blockIdx.y;                 // chunk index (linear ID = xb + j*XB: in-order in j)
    const int b  = c >> 9;                     // c / D4
    const int d4 = c & (D4 - 1);

    const size_t base = ((size_t)b * S + (size_t)j * L) * D4 + d4;
    const float4* p = x + base;

    // ---- Phase 1: local EMA over this chunk (zero init) ----
    float f0 = 0.f, f1 = 0.f, f2 = 0.f, f3 = 0.f;
#pragma unroll 8
    for (int t = 0; t < L; ++t) {
        float4 v = p[(size_t)t * D4];
        f0 = kA * f0 + kOm * v.x;
        f1 = kA * f1 + kOm * v.y;
        f2 = kA * f2 + kOm * v.z;
        f3 = kA * f3 + kOm * v.w;
    }

    // ---- Phase 2: publish aggregate, then release the flag ----
    part[(size_t)j * NCOL4 + c] = make_float4(f0, f1, f2, f3);
    __threadfence();               // make row visible at agent scope
    __syncthreads();               // all 256 threads' stores fenced
    if (threadIdx.x == 0)
        __hip_atomic_store(&flags[xb * NCHUNK + j], 1,
                           __ATOMIC_RELEASE, __HIP_MEMORY_SCOPE_AGENT);

    // ---- Phase 3: wait for ALL predecessor chunks of this column-block ----
    float E0 = 0.f, E1 = 0.f, E2 = 0.f, E3 = 0.f;
    if (j > 0) {
        const int t = threadIdx.x;             // NCHUNK <= 128 < BLOCK: one flag per lane
        for (;;) {
            int ok = 1;
            if (t < j)
                ok = (__hip_atomic_load(&flags[xb * NCHUNK + t],
                                        __ATOMIC_ACQUIRE, __HIP_MEMORY_SCOPE_AGENT) != 0);
            if (__syncthreads_and(ok)) break;  // uniform exit
            __builtin_amdgcn_s_sleep(2);
        }
        __threadfence();                       // invalidate before bulk row reads

        // ---- Phase 4: carry Horner, ascending — numerics identical to old K2 ----
        const float4* w = part + c;
#pragma unroll 4
        for (int i = 0; i < j; ++i) {          // j block-uniform; loads pipeline 4-deep
            float4 f = w[(size_t)i * NCOL4];
            E0 = E0 * aL + f.x;
            E1 = E1 * aL + f.y;
            E2 = E2 * aL + f.z;
            E3 = E3 * aL + f.w;
        }
    }

    // ---- Phase 5: rescan chunk with carry (x chunk is L2/L3-hot), write out ----
    v4f* q = (v4f*)(out + base);
#pragma unroll 8
    for (int t = 0; t < L; ++t) {
        float4 v = p[(size_t)t * D4];
        E0 = kA * E0 + kOm * v.x;
        E1 = kA * E1 + kOm * v.y;
        E2 = kA * E2 + kOm * v.z;
        E3 = kA * E3 + kOm * v.w;
        v4f o = {E0, E1, E2, E3};
        __builtin_nontemporal_store(o, &q[(size_t)t * D4]);
    }
}

template <int NCHUNK>
void launch(const float4* x, float4* out, float4* ws, hipStream_t stream) {
    int* flags = (int*)(ws + (size_t)NCHUNK * NCOL4);
    const int nflags = XB * NCHUNK;
    zero_flags<<<dim3((nflags + 255) / 256), dim3(256), 0, stream>>>(flags, nflags);
    cema_fused<NCHUNK><<<dim3(XB, NCHUNK), dim3(BLOCK), 0, stream>>>(x, out, ws, flags);
}

} // namespace

extern "C" void kernel_launch(void* const* d_in, const int* in_sizes, int n_in,
                              void* d_out, int out_size, void* d_ws, size_t ws_size,
                              hipStream_t stream) {
    const float4* x = (const float4*)d_in[0];
    float4* out     = (float4*)d_out;
    float4* ws      = (float4*)d_ws;

    auto need = [](size_t nchunk) {
        return nchunk * NCOL4 * sizeof(float4) + (size_t)XB * nchunk * sizeof(int);
    };
    if (ws_size >= need(128))      launch<128>(x, out, ws, stream);
    else if (ws_size >= need(64))  launch<64>(x, out, ws, stream);
    else                           launch<32>(x, out, ws, stream);
}

// Round 2
// 261.106 us; speedup vs baseline: 2.3147x; 2.3147x over previous
//
#include <hip/hip_runtime.h>

// EMA recurrence over s for x[4, 4096, 2048] fp32.
// Exact three-pass chunked scan (no cross-block sync — round-1 showed
// agent-scope acquire/release polling costs ~300 us on gfx950 due to
// per-XCD L2 invalidate storms):
//   K1:   per-(col4, chunk) local EMA (zero init) -> chunk finals f_j in ws
//   Kmid: tiny sequential scan over the 128 finals rows -> exclusive carry
//         rows E_{j-1} (bit-identical FMA order to the old per-block Horner)
//   K3:   read ONE carry row + rescan chunk from x, nontemporal-store out.
//         Removes the O(NCHUNK^2) Horner re-reads and the j=127 latency tail.

namespace {

constexpr int B  = 4;
constexpr int S  = 4096;
constexpr int D  = 2048;
constexpr int D4 = D / 4;          // 512 float4 per (b,s) row
constexpr int NCOL4 = B * D4;      // 2048 float4-columns
constexpr int NCOLS = NCOL4 * 4;   // 8192 scalar columns
constexpr int BLOCK = 256;

typedef float v4f __attribute__((ext_vector_type(4)));

// Match the reference's fp32 constants exactly.
constexpr float kA  = 0.99f;
constexpr float kOm = (float)(1.0 - 0.99);      // 0.009999999776482582f

// 0.99^L in double, L a power of two (repeated squaring), then round to float.
constexpr double alpha_pow_pow2(int l) {
    double t = 0.99;
    while (l > 1) { t *= t; l >>= 1; }
    return t;
}

template <int NCHUNK>
__global__ __launch_bounds__(BLOCK)
void cema_k1_finals(const float4* __restrict__ x, float4* __restrict__ finals) {
    constexpr int L = S / NCHUNK;
    const int c  = blockIdx.x * BLOCK + threadIdx.x;   // col4 index
    const int j  = blockIdx.y;                         // chunk index
    const int b  = c >> 9;                             // c / D4
    const int d4 = c & (D4 - 1);

    const size_t base = ((size_t)b * S + (size_t)j * L) * D4 + d4;
    const float4* p = x + base;

    float e0 = 0.f, e1 = 0.f, e2 = 0.f, e3 = 0.f;
#pragma unroll 8
    for (int t = 0; t < L; ++t) {
        float4 v = p[(size_t)t * D4];
        e0 = kA * e0 + kOm * v.x;
        e1 = kA * e1 + kOm * v.y;
        e2 = kA * e2 + kOm * v.z;
        e3 = kA * e3 + kOm * v.w;
    }
    finals[(size_t)j * NCOL4 + c] = make_float4(e0, e1, e2, e3);
}

// Sequential scan over chunk finals -> exclusive carries.
// One thread per SCALAR column (8192 threads = 32 blocks). Loads/stores are
// fully coalesced (row-major, stride NCOLS). carry[j] = Horner over
// f_0..f_{j-1} with alpha^L — exactly the value the old K2 computed, with
// the identical fma sequence -> bit-identical results.
template <int NCHUNK>
__global__ __launch_bounds__(BLOCK)
void cema_scan_finals(const float* __restrict__ finals, float* __restrict__ carry) {
    constexpr int L = S / NCHUNK;
    constexpr float aL = (float)alpha_pow_pow2(L);

    const int col = blockIdx.x * BLOCK + threadIdx.x;  // 0..NCOLS-1
    float E = 0.f;
#pragma unroll 8
    for (int j = 0; j < NCHUNK; ++j) {
        float f = finals[(size_t)j * NCOLS + col];
        carry[(size_t)j * NCOLS + col] = E;            // exclusive: E_{j-1}
        E = E * aL + f;
    }
}

template <int NCHUNK>
__global__ __launch_bounds__(BLOCK)
void cema_k3_apply(const float4* __restrict__ x, const float4* __restrict__ carry,
                   float4* __restrict__ out) {
    constexpr int L = S / NCHUNK;

    const int c  = blockIdx.x * BLOCK + threadIdx.x;
    const int j  = blockIdx.y;
    const int b  = c >> 9;
    const int d4 = c & (D4 - 1);

    // Carry into chunk j — one coalesced row read (L2/L3 resident).
    float4 E4 = carry[(size_t)j * NCOL4 + c];
    float E0 = E4.x, E1 = E4.y, E2 = E4.z, E3 = E4.w;

    const size_t base = ((size_t)b * S + (size_t)j * L) * D4 + d4;
    const float4* p = x + base;
    v4f* q = (v4f*)(out + base);

#pragma unroll 8
    for (int t = 0; t < L; ++t) {
        float4 v = p[(size_t)t * D4];
        E0 = kA * E0 + kOm * v.x;
        E1 = kA * E1 + kOm * v.y;
        E2 = kA * E2 + kOm * v.z;
        E3 = kA * E3 + kOm * v.w;
        v4f o = {E0, E1, E2, E3};
        __builtin_nontemporal_store(o, &q[(size_t)t * D4]);
    }
}

template <int NCHUNK>
void launch(const float4* x, float4* ws, float4* out, hipStream_t stream) {
    float4* finals = ws;
    float4* carry  = ws + (size_t)NCHUNK * NCOL4;

    dim3 grid(NCOL4 / BLOCK, NCHUNK);
    cema_k1_finals<NCHUNK><<<grid, BLOCK, 0, stream>>>(x, finals);
    cema_scan_finals<NCHUNK><<<dim3(NCOLS / BLOCK), BLOCK, 0, stream>>>(
        (const float*)finals, (float*)carry);
    cema_k3_apply<NCHUNK><<<grid, BLOCK, 0, stream>>>(x, carry, out);
}

} // namespace

extern "C" void kernel_launch(void* const* d_in, const int* in_sizes, int n_in,
                              void* d_out, int out_size, void* d_ws, size_t ws_size,
                              hipStream_t stream) {
    const float4* x  = (const float4*)d_in[0];
    float4* out      = (float4*)d_out;
    float4* ws       = (float4*)d_ws;

    auto need = [](size_t nchunk) {
        return 2 * nchunk * (size_t)NCOL4 * sizeof(float4);
    };
    if (ws_size >= need(128))      launch<128>(x, ws, out, stream);
    else if (ws_size >= need(64))  launch<64>(x, ws, out, stream);
    else                           launch<32>(x, ws, out, stream);
}